// Round 6
// baseline (724.806 us; speedup 1.0000x reference)
//
#include <hip/hip_runtime.h>
#include <math.h>

#define TPB 256
static inline int cdiv(int a, int b) { return (a + b - 1) / b; }

typedef __attribute__((ext_vector_type(8))) short short8;
typedef __attribute__((ext_vector_type(4))) float floatx4;

__device__ __forceinline__ float bf2f(ushort u) {
    union { unsigned int u; float f; } v; v.u = ((unsigned int)u) << 16; return v.f;
}
__device__ __forceinline__ ushort f2bf(float f) {
    union { float f; unsigned int u; } v; v.f = f;
    unsigned int r = (v.u + 0x7FFFu + ((v.u >> 16) & 1u)) >> 16;
    return (ushort)r;
}

// Concatenated pyramid layout: rows [0,16384) l0(H=64), [16384,20480) l1(H=32),
// [20480,21504) l2(H=16), [21504,21760) l3(H=8), [21760,21824) l4(H=4).
#define CONC_ROWS 21824
__device__ __forceinline__ void lvl_of(int row, int& lvl, int& base) {
    lvl = 0; base = 0;
    if (row >= 16384) { lvl = 1; base = 16384; }
    if (row >= 20480) { lvl = 2; base = 20480; }
    if (row >= 21504) { lvl = 3; base = 21504; }
    if (row >= 21760) { lvl = 4; base = 21760; }
}
__constant__ int LOFFc[5] = {0, 36864, 46080, 48384, 48960};

// ---------------------------------------------------------------------------
// Weight packing. Frag order: Bp[(((tap*3+ks)*4+g)*Ntot + n)*8 + j]
//   = W[co=n][ci=ks*32+g*8+j][tap]
// ---------------------------------------------------------------------------
__global__ void pack3_k(const float* __restrict__ w, ushort* __restrict__ Bp,
                        int Ntot, int CO, int total) {
    int idx = blockIdx.x * blockDim.x + threadIdx.x;
    if (idx >= total) return;
    int j = idx & 7; int t = idx >> 3;
    int n = t % Ntot; t /= Ntot;
    int g = t & 3; t >>= 2;
    int ks = t % 3; int tap = t / 3;
    int ci = ks * 32 + g * 8 + j;
    float v = (ci < 88 && n < CO) ? w[((size_t)n * 88 + ci) * 9 + tap] : 0.f;
    Bp[idx] = f2bf(v);
}

__global__ void pack_tw8_k(const float* __restrict__ rw, const float* __restrict__ cw,
                           ushort* __restrict__ Bp) {
    int idx = blockIdx.x * blockDim.x + threadIdx.x;
    if (idx >= 8 * 82944) return;
    int i = idx / 82944; int r = idx - i * 82944;
    const float* w = (i < 4) ? rw + (size_t)i * 69696 : cw + (size_t)(i - 4) * 69696;
    int j = r & 7; int t = r >> 3;
    int n = t % 96; t /= 96;
    int g = t & 3; t >>= 2;
    int ks = t % 3; int tap = t / 3;
    int ci = ks * 32 + g * 8 + j;
    float v = (ci < 88 && n < 88) ? w[((size_t)n * 88 + ci) * 9 + tap] : 0.f;
    Bp[idx] = f2bf(v);
}

// 24 BiFPN pointwise convs -> 24 x [3ks][4g][96n][8j]
__global__ void pack_pw_all_k(const float* __restrict__ pw, ushort* __restrict__ Bp,
                              int total) {
    int idx = blockIdx.x * blockDim.x + threadIdx.x;
    if (idx >= total) return;
    int cid = idx / 9216; int r = idx - cid * 9216;
    int j = r & 7; int t = r >> 3;
    int n = t % 96; t /= 96;
    int g = t & 3; int ks = t >> 2;
    int ci = ks * 32 + g * 8 + j;
    float v = (ci < 88 && n < 88) ? pw[(size_t)cid * 7744 + n * 88 + ci] : 0.f;
    Bp[idx] = f2bf(v);
}

// 5 lateral 1x1 convs, K padded to 32: per level [KS][4g][96n][8j]
__global__ void pack_lat_k(const float* __restrict__ w3, const float* __restrict__ w4,
                           const float* __restrict__ w5, const float* __restrict__ w6,
                           const float* __restrict__ w7, ushort* __restrict__ Bp) {
    int idx = blockIdx.x * blockDim.x + threadIdx.x;
    if (idx >= 76800) return;
    int l, off;
    if (idx < 6144)       { l = 0; off = 0; }
    else if (idx < 15360) { l = 1; off = 6144; }
    else if (idx < 27648) { l = 2; off = 15360; }
    else if (idx < 46080) { l = 3; off = 27648; }
    else                  { l = 4; off = 46080; }
    const float* w = l == 0 ? w3 : l == 1 ? w4 : l == 2 ? w5 : l == 3 ? w6 : w7;
    const int cins[5] = {40, 80, 112, 192, 320};
    int Cin = cins[l];
    int r = idx - off;
    int j = r & 7; int t = r >> 3;
    int n = t % 96; t /= 96;
    int g = t & 3; int ks = t >> 2;
    int ci = ks * 32 + g * 8 + j;
    float v = (ci < Cin && n < 88) ? w[(size_t)n * Cin + ci] : 0.f;
    Bp[idx] = f2bf(v);
}

// ---------------------------------------------------------------------------
// Lateral conv as MFMA implicit GEMM: NCHW fp32 -> NHWC96 bf16, no act.
// ---------------------------------------------------------------------------
__global__ __launch_bounds__(256)
void lateral_mfma_k(const float* __restrict__ x, const ushort* __restrict__ Bp,
                    const float* __restrict__ bias, ushort* __restrict__ out,
                    int Cin, int KS, int logHH) {
    __shared__ ushort As[64 * 40];
    int tid = threadIdx.x;
    int m0 = blockIdx.x * 64;
    int lane = tid & 63, l15 = lane & 15, g = (lane >> 4) & 3;
    int wave = tid >> 6, wm = wave & 1, wn = wave >> 1;
    floatx4 acc[2][3];
#pragma unroll
    for (int a = 0; a < 2; ++a)
#pragma unroll
        for (int b = 0; b < 3; ++b) acc[a][b] = (floatx4){0.f, 0.f, 0.f, 0.f};
    const short8* Bq = (const short8*)Bp;

    int p = m0 + lane;
    int n = p >> logHH, pp = p & ((1 << logHH) - 1);
    const float* xp = x + (((size_t)n * Cin) << logHH) + pp;

    for (int ks = 0; ks < KS; ++ks) {
        __syncthreads();
#pragma unroll
        for (int it = 0; it < 8; ++it) {
            int ciL = (tid >> 6) + it * 4;
            int ci = ks * 32 + ciL;
            float v = (ci < Cin) ? xp[(size_t)ci << logHH] : 0.f;
            As[lane * 40 + ciL] = f2bf(v);
        }
        __syncthreads();
        short8 a0 = *(const short8*)(&As[(wm * 32 + l15) * 40 + g * 8]);
        short8 a1 = *(const short8*)(&As[(wm * 32 + 16 + l15) * 40 + g * 8]);
        int bbase = (ks * 4 + g) * 96 + wn * 48 + l15;
#pragma unroll
        for (int nf = 0; nf < 3; ++nf) {
            short8 b = Bq[bbase + nf * 16];
            acc[0][nf] = __builtin_amdgcn_mfma_f32_16x16x32_bf16(a0, b, acc[0][nf], 0, 0, 0);
            acc[1][nf] = __builtin_amdgcn_mfma_f32_16x16x32_bf16(a1, b, acc[1][nf], 0, 0, 0);
        }
    }
    float bc[3];
#pragma unroll
    for (int nf = 0; nf < 3; ++nf) {
        int c = wn * 48 + nf * 16 + l15;
        bc[nf] = (c < 88) ? bias[c] : 0.f;
    }
#pragma unroll
    for (int mf = 0; mf < 2; ++mf)
#pragma unroll
        for (int r = 0; r < 4; ++r) {
            int pl = m0 + wm * 32 + mf * 16 + g * 4 + r;
#pragma unroll
            for (int nf = 0; nf < 3; ++nf) {
                int c = wn * 48 + nf * 16 + l15;
                out[(size_t)pl * 96 + c] = f2bf(acc[mf][nf][r] + bc[nf]);
            }
        }
}

// ---------------------------------------------------------------------------
// Fully fused BiFPN step: fuse-op -> depthwise 3x3 -> pointwise MFMA + ReLU.
// MODE 0: 2-in (a + up2(b)); 1: 2-in (a + down2(b)); 2: 3-in (a + b + down2(c)).
// ---------------------------------------------------------------------------
template <int MODE>
__global__ __launch_bounds__(256, 2)
void sepconv_k(const ushort* __restrict__ a, const ushort* __restrict__ bsrc,
               const ushort* __restrict__ csrc, const float* __restrict__ fw,
               const float* __restrict__ dww, const ushort* __restrict__ Bp,
               const float* __restrict__ pbias, ushort* __restrict__ out,
               int logW) {
    __shared__ ushort Fs[195 * 104];   // fused input + halo; row 194 = zeros
    __shared__ ushort Ds[64 * 104];    // depthwise output (pw A-tile)
    __shared__ ushort Dwb[108 * 8];    // dw weights bf16 [cg][tap][8]
    int tid = threadIdx.x;
    int W = 1 << logW, HH = W * W, log2HH = 2 * logW;
    int Mlv = 4 * HH;
    int HB = W + 1;
    int RS = 64 + 2 * HB;
    int pl0 = blockIdx.x * 64;
    float w0 = fmaxf(fw[0], 0.f), w1 = fmaxf(fw[1], 0.f);
    float w2 = (MODE == 2) ? fmaxf(fw[2], 0.f) : 0.f;
    float inv = 1.f / (w0 + w1 + w2 + 1e-4f);
    float w0i = w0 * inv, w1i = w1 * inv, w2i = w2 * inv;

    if (tid < 13) *(uint4*)(&Fs[194 * 104 + tid * 8]) = (uint4){0u, 0u, 0u, 0u};
    for (int i = tid; i < 108; i += 256) {
        int cg = i / 9, tap = i - cg * 9;
        ushort tmp[8];
#pragma unroll
        for (int j = 0; j < 8; ++j) {
            int c = cg * 8 + j;
            tmp[j] = (c < 88) ? f2bf(dww[c * 9 + tap]) : (ushort)0;
        }
        *(uint4*)(&Dwb[i * 8]) = *(uint4*)tmp;
    }
    for (int i = tid; i < RS * 12; i += 256) {
        int row = i / 12, cg = i - row * 12;
        int pl = pl0 - HB + row;
        uint4 res = {0u, 0u, 0u, 0u};
        if (pl >= 0 && pl < Mlv) {
            int n = pl >> log2HH, pp = pl & (HH - 1);
            int y = pp >> logW, x = pp & (W - 1);
            uint4 av = *(const uint4*)(a + (size_t)pl * 96 + cg * 8);
            const ushort* au = (const ushort*)&av;
            float f[8];
            if (MODE == 0) {
                int Wh = W >> 1;
                int bp = (n << (log2HH - 2)) + (y >> 1) * Wh + (x >> 1);
                uint4 bv = *(const uint4*)(bsrc + (size_t)bp * 96 + cg * 8);
                const ushort* bu = (const ushort*)&bv;
#pragma unroll
                for (int j = 0; j < 8; ++j)
                    f[j] = w0i * bf2f(au[j]) + w1i * bf2f(bu[j]);
            } else {
                int W2 = W << 1;
                const ushort* q = (MODE == 1 ? bsrc : csrc) +
                    ((size_t)((n << (log2HH + 2)) + (2 * y) * W2 + 2 * x)) * 96 + cg * 8;
                uint4 q0 = *(const uint4*)(q);
                uint4 q1 = *(const uint4*)(q + 96);
                uint4 q2 = *(const uint4*)(q + (size_t)W2 * 96);
                uint4 q3 = *(const uint4*)(q + (size_t)W2 * 96 + 96);
                const ushort* u0 = (const ushort*)&q0; const ushort* u1 = (const ushort*)&q1;
                const ushort* u2 = (const ushort*)&q2; const ushort* u3 = (const ushort*)&q3;
                if (MODE == 1) {
#pragma unroll
                    for (int j = 0; j < 8; ++j) {
                        float m = fmaxf(fmaxf(bf2f(u0[j]), bf2f(u1[j])),
                                        fmaxf(bf2f(u2[j]), bf2f(u3[j])));
                        f[j] = w0i * bf2f(au[j]) + w1i * m;
                    }
                } else {
                    uint4 b2v = *(const uint4*)(bsrc + (size_t)pl * 96 + cg * 8);
                    const ushort* b2u = (const ushort*)&b2v;
#pragma unroll
                    for (int j = 0; j < 8; ++j) {
                        float m = fmaxf(fmaxf(bf2f(u0[j]), bf2f(u1[j])),
                                        fmaxf(bf2f(u2[j]), bf2f(u3[j])));
                        f[j] = w0i * bf2f(au[j]) + w1i * bf2f(b2u[j]) + w2i * m;
                    }
                }
            }
            ushort tmp[8];
#pragma unroll
            for (int j = 0; j < 8; ++j) tmp[j] = f2bf(f[j]);
            res = *(uint4*)tmp;
        }
        *(uint4*)(&Fs[row * 104 + cg * 8]) = res;
    }
    __syncthreads();
    // depthwise 3x3 -> Ds
    for (int i = tid; i < 768; i += 256) {
        int row = i / 12, cg = i - row * 12;
        int pl = pl0 + row;
        int pp = pl & (HH - 1);
        int y = pp >> logW, x = pp & (W - 1);
        float acc8[8] = {0.f, 0.f, 0.f, 0.f, 0.f, 0.f, 0.f, 0.f};
        if (cg < 11) {
#pragma unroll
            for (int tap = 0; tap < 9; ++tap) {
                int dy = tap / 3 - 1, dx = tap % 3 - 1;
                int sy = y + dy, sx = x + dx;
                bool pred = ((unsigned)sy < (unsigned)W) && ((unsigned)sx < (unsigned)W);
                int rsel = pred ? (row + HB + dy * W + dx) : 194;
                short8 fv = *(const short8*)(&Fs[rsel * 104 + cg * 8]);
                short8 wv = *(const short8*)(&Dwb[(cg * 9 + tap) * 8]);
#pragma unroll
                for (int j = 0; j < 8; ++j)
                    acc8[j] = fmaf(bf2f((ushort)fv[j]), bf2f((ushort)wv[j]), acc8[j]);
            }
        }
        ushort tmp[8];
#pragma unroll
        for (int j = 0; j < 8; ++j) tmp[j] = f2bf(acc8[j]);
        *(uint4*)(&Ds[row * 104 + cg * 8]) = *(uint4*)tmp;
    }
    __syncthreads();
    // pointwise MFMA (Mt=64, N=96, K=96) + bias + ReLU
    int lane = tid & 63, l15 = lane & 15, g = (lane >> 4) & 3;
    int wave = tid >> 6, wm = wave & 1, wn = wave >> 1;
    floatx4 acc[2][3];
#pragma unroll
    for (int aa = 0; aa < 2; ++aa)
#pragma unroll
        for (int bb = 0; bb < 3; ++bb) acc[aa][bb] = (floatx4){0.f, 0.f, 0.f, 0.f};
    const short8* Bq = (const short8*)Bp;
#pragma unroll
    for (int ks = 0; ks < 3; ++ks) {
        int k = ks * 32 + g * 8;
        short8 a0 = *(const short8*)(&Ds[(wm * 32 + l15) * 104 + k]);
        short8 a1 = *(const short8*)(&Ds[(wm * 32 + 16 + l15) * 104 + k]);
        int bbase = (ks * 4 + g) * 96 + wn * 48 + l15;
#pragma unroll
        for (int nf = 0; nf < 3; ++nf) {
            short8 b = Bq[bbase + nf * 16];
            acc[0][nf] = __builtin_amdgcn_mfma_f32_16x16x32_bf16(a0, b, acc[0][nf], 0, 0, 0);
            acc[1][nf] = __builtin_amdgcn_mfma_f32_16x16x32_bf16(a1, b, acc[1][nf], 0, 0, 0);
        }
    }
    float bc[3];
#pragma unroll
    for (int nf = 0; nf < 3; ++nf) {
        int c = wn * 48 + nf * 16 + l15;
        bc[nf] = (c < 88) ? pbias[c] : 0.f;
    }
#pragma unroll
    for (int mf = 0; mf < 2; ++mf)
#pragma unroll
        for (int r = 0; r < 4; ++r) {
            int pl = pl0 + wm * 32 + mf * 16 + g * 4 + r;
#pragma unroll
            for (int nf = 0; nf < 3; ++nf) {
                int c = wn * 48 + nf * 16 + l15;
                out[(size_t)pl * 96 + c] = f2bf(fmaxf(acc[mf][nf][r] + bc[nf], 0.f));
            }
        }
}

// ---------------------------------------------------------------------------
// Direct-load tower conv 3x3 88->88 + bias + ReLU. No LDS; B-fragments
// register-prefetched one tap ahead (hides L2 latency); A loaded per tap
// (L1-resident after tap 0). Dual-head via blockIdx.y.
// ---------------------------------------------------------------------------
__global__ __launch_bounds__(256, 3)
void tower_direct_k(const ushort* __restrict__ inR, const ushort* __restrict__ inC,
                    const ushort* __restrict__ BpR, const ushort* __restrict__ BpC,
                    const float* __restrict__ bR, const float* __restrict__ bC,
                    ushort* __restrict__ outR, ushort* __restrict__ outC,
                    const ushort* __restrict__ zb) {
    int head = blockIdx.y;
    const ushort* in = head ? inC : inR;
    const short8* Bq = (const short8*)(head ? BpC : BpR);
    const float* bias = head ? bC : bR;
    ushort* out = head ? outC : outR;
    int tid = threadIdx.x;
    int m0 = blockIdx.x * 64;
    int lvl, base; lvl_of(m0, lvl, base);
    int logW = 6 - lvl, W = 1 << logW, HH = W * W;
    int pl0 = m0 - base;
    int lane = tid & 63, l15 = lane & 15, g = (lane >> 4) & 3;
    int wave = tid >> 6, wm = wave & 1, wn = wave >> 1;
    int ym[2], xm[2];
    const ushort* pbase[2];
#pragma unroll
    for (int mf = 0; mf < 2; ++mf) {
        int pl = pl0 + wm * 32 + mf * 16 + l15;
        int pp = pl & (HH - 1);
        ym[mf] = pp >> logW; xm[mf] = pp & (W - 1);
        pbase[mf] = in + (size_t)(base + pl) * 96 + g * 8;
    }
    const ushort* zbg = zb + g * 8;
    int bcol = wn * 48 + l15;

    floatx4 acc[2][3];
#pragma unroll
    for (int aa = 0; aa < 2; ++aa)
#pragma unroll
        for (int bb = 0; bb < 3; ++bb) acc[aa][bb] = (floatx4){0.f, 0.f, 0.f, 0.f};

    short8 Bc[3][3], Bn[3][3];
#pragma unroll
    for (int ks = 0; ks < 3; ++ks) {
        int bb = (ks * 4 + g) * 96 + bcol;
#pragma unroll
        for (int nf = 0; nf < 3; ++nf) Bc[ks][nf] = Bq[bb + nf * 16];
    }
#pragma unroll
    for (int tap = 0; tap < 9; ++tap) {
        if (tap < 8) {
#pragma unroll
            for (int ks = 0; ks < 3; ++ks) {
                int bb = (((tap + 1) * 3 + ks) * 4 + g) * 96 + bcol;
#pragma unroll
                for (int nf = 0; nf < 3; ++nf) Bn[ks][nf] = Bq[bb + nf * 16];
            }
        }
        const int dy = tap / 3 - 1, dx = tap % 3 - 1;
        int off96 = (dy * W + dx) * 96;
        const ushort* ap[2];
#pragma unroll
        for (int mf = 0; mf < 2; ++mf) {
            bool pred = ((unsigned)(ym[mf] + dy) < (unsigned)W) &&
                        ((unsigned)(xm[mf] + dx) < (unsigned)W);
            ap[mf] = pred ? (pbase[mf] + off96) : zbg;
        }
        short8 A0[3], A1[3];
#pragma unroll
        for (int ks = 0; ks < 3; ++ks) {
            A0[ks] = *(const short8*)(ap[0] + ks * 32);
            A1[ks] = *(const short8*)(ap[1] + ks * 32);
        }
#pragma unroll
        for (int ks = 0; ks < 3; ++ks)
#pragma unroll
            for (int nf = 0; nf < 3; ++nf) {
                acc[0][nf] = __builtin_amdgcn_mfma_f32_16x16x32_bf16(A0[ks], Bc[ks][nf], acc[0][nf], 0, 0, 0);
                acc[1][nf] = __builtin_amdgcn_mfma_f32_16x16x32_bf16(A1[ks], Bc[ks][nf], acc[1][nf], 0, 0, 0);
            }
        if (tap < 8) {
#pragma unroll
            for (int ks = 0; ks < 3; ++ks)
#pragma unroll
                for (int nf = 0; nf < 3; ++nf) Bc[ks][nf] = Bn[ks][nf];
        }
    }
    float bc[3];
#pragma unroll
    for (int nf = 0; nf < 3; ++nf) {
        int c = wn * 48 + nf * 16 + l15;
        bc[nf] = (c < 88) ? bias[c] : 0.f;
    }
#pragma unroll
    for (int mf = 0; mf < 2; ++mf)
#pragma unroll
        for (int r = 0; r < 4; ++r) {
            int pl = pl0 + wm * 32 + mf * 16 + g * 4 + r;
#pragma unroll
            for (int nf = 0; nf < 3; ++nf) {
                int c = wn * 48 + nf * 16 + l15;
                out[(size_t)(base + pl) * 96 + c] = f2bf(fmaxf(acc[mf][nf][r] + bc[nf], 0.f));
            }
        }
}

// ---------------------------------------------------------------------------
// Fused output heads: grid (341, 10). y=0 -> regression (Ntot=96, OC=4),
// y=1..9 -> classification n-block y-1 (Ntot=864, OC=90, sigmoid).
// B register-prefetched one tap ahead; nontemporal stores (no RFO).
// ---------------------------------------------------------------------------
__global__ __launch_bounds__(256, 3)
void heads_out_k(const ushort* __restrict__ xr, const ushort* __restrict__ xc,
                 const ushort* __restrict__ BpR, const ushort* __restrict__ BpC,
                 const float* __restrict__ bR, const float* __restrict__ bC,
                 float* __restrict__ outR, float* __restrict__ outC,
                 const ushort* __restrict__ zb) {
    int yb = blockIdx.y;
    bool isReg = (yb == 0);
    const ushort* in = isReg ? xr : xc;
    const short8* Bq = (const short8*)(isReg ? BpR : BpC);
    const float* bias = isReg ? bR : bC;
    float* outb = isReg ? outR : outC;
    const int Ntot = isReg ? 96 : 864;
    const int C9 = isReg ? 36 : 810;
    const int OC = isReg ? 4 : 90;
    const int n0b = isReg ? 0 : (yb - 1) * 96;

    int tid = threadIdx.x;
    int m0 = blockIdx.x * 64;
    int lvl, base; lvl_of(m0, lvl, base);
    int logW = 6 - lvl, W = 1 << logW, HH = W * W, log2HH = 2 * logW;
    int pl0 = m0 - base;
    int lane = tid & 63, l15 = lane & 15, g = (lane >> 4) & 3;
    int wave = tid >> 6, wm = wave & 1, wn = wave >> 1;
    int ym[2], xm[2];
    const ushort* pbase[2];
#pragma unroll
    for (int mf = 0; mf < 2; ++mf) {
        int pl = pl0 + wm * 32 + mf * 16 + l15;
        int pp = pl & (HH - 1);
        ym[mf] = pp >> logW; xm[mf] = pp & (W - 1);
        pbase[mf] = in + (size_t)(base + pl) * 96 + g * 8;
    }
    const ushort* zbg = zb + g * 8;
    int bcol = n0b + wn * 48 + l15;

    floatx4 acc[2][3];
#pragma unroll
    for (int aa = 0; aa < 2; ++aa)
#pragma unroll
        for (int bb = 0; bb < 3; ++bb) acc[aa][bb] = (floatx4){0.f, 0.f, 0.f, 0.f};

    short8 Bc[3][3], Bn[3][3];
#pragma unroll
    for (int ks = 0; ks < 3; ++ks) {
        int bb = (ks * 4 + g) * Ntot + bcol;
#pragma unroll
        for (int nf = 0; nf < 3; ++nf) Bc[ks][nf] = Bq[bb + nf * 16];
    }
#pragma unroll
    for (int tap = 0; tap < 9; ++tap) {
        if (tap < 8) {
#pragma unroll
            for (int ks = 0; ks < 3; ++ks) {
                int bb = (((tap + 1) * 3 + ks) * 4 + g) * Ntot + bcol;
#pragma unroll
                for (int nf = 0; nf < 3; ++nf) Bn[ks][nf] = Bq[bb + nf * 16];
            }
        }
        const int dy = tap / 3 - 1, dx = tap % 3 - 1;
        int off96 = (dy * W + dx) * 96;
        const ushort* ap[2];
#pragma unroll
        for (int mf = 0; mf < 2; ++mf) {
            bool pred = ((unsigned)(ym[mf] + dy) < (unsigned)W) &&
                        ((unsigned)(xm[mf] + dx) < (unsigned)W);
            ap[mf] = pred ? (pbase[mf] + off96) : zbg;
        }
        short8 A0[3], A1[3];
#pragma unroll
        for (int ks = 0; ks < 3; ++ks) {
            A0[ks] = *(const short8*)(ap[0] + ks * 32);
            A1[ks] = *(const short8*)(ap[1] + ks * 32);
        }
#pragma unroll
        for (int ks = 0; ks < 3; ++ks)
#pragma unroll
            for (int nf = 0; nf < 3; ++nf) {
                acc[0][nf] = __builtin_amdgcn_mfma_f32_16x16x32_bf16(A0[ks], Bc[ks][nf], acc[0][nf], 0, 0, 0);
                acc[1][nf] = __builtin_amdgcn_mfma_f32_16x16x32_bf16(A1[ks], Bc[ks][nf], acc[1][nf], 0, 0, 0);
            }
        if (tap < 8) {
#pragma unroll
            for (int ks = 0; ks < 3; ++ks)
#pragma unroll
                for (int nf = 0; nf < 3; ++nf) Bc[ks][nf] = Bn[ks][nf];
        }
    }
#pragma unroll
    for (int nf = 0; nf < 3; ++nf) {
        int c = n0b + wn * 48 + nf * 16 + l15;
        if (c >= C9) continue;
        float bcv = bias[c];
        int a = c / OC, kk = c - a * OC;
#pragma unroll
        for (int mf = 0; mf < 2; ++mf)
#pragma unroll
            for (int r = 0; r < 4; ++r) {
                int pl = pl0 + wm * 32 + mf * 16 + g * 4 + r;
                int n = pl >> log2HH, pp = pl & (HH - 1);
                float v = acc[mf][nf][r] + bcv;
                if (!isReg) v = 1.f / (1.f + expf(-v));
                __builtin_nontemporal_store(
                    v, &outb[((size_t)n * 49104 + LOFFc[lvl] + (size_t)pp * 9 + a) * OC + kk]);
            }
    }
}

// ---------------------------------------------------------------------------
// anchors + zero-buffer init (zb: 96 ushorts = 48 uints)
__global__ void anchors_k(float* __restrict__ out, ushort* __restrict__ zb) {
    int idx = blockIdx.x * blockDim.x + threadIdx.x;
    if (idx < 48) ((unsigned int*)zb)[idx] = 0u;
    if (idx >= 49104) return;
    const int offs[6] = {0, 36864, 46080, 48384, 48960, 49104};
    int l = 0;
    while (idx >= offs[l + 1]) ++l;
    int j = idx - offs[l];
    int a = j % 9;
    int p = j / 9;
    int fs = 64 >> l;
    int stride = 8 << l;
    float size = (float)(32 << l);
    int ix = p % fs, iy = p / fs;
    float cx = (ix + 0.5f) * (float)stride;
    float cy = (iy + 0.5f) * (float)stride;
    const float scl[3] = {1.0f, 1.2599210498948732f, 1.5874010519681994f};
    const float sqr[3] = {0.7071067811865476f, 1.0f, 1.4142135623730951f};
    int r = a / 3, s = a % 3;
    float w = size * scl[s] / sqr[r];
    float h = size * scl[s] * sqr[r];
    float* o = out + (size_t)idx * 4;
    o[0] = cx - 0.5f * w;
    o[1] = cy - 0.5f * h;
    o[2] = cx + 0.5f * w;
    o[3] = cy + 0.5f * h;
}

// ---------------------------------------------------------------------------

extern "C" void kernel_launch(void* const* d_in, const int* in_sizes, int n_in,
                              void* d_out, int out_size, void* d_ws, size_t ws_size,
                              hipStream_t stream) {
    const float* c_in[5]  = {(const float*)d_in[0],  (const float*)d_in[3],
                             (const float*)d_in[6],  (const float*)d_in[9],
                             (const float*)d_in[12]};
    const float* lat_w[5] = {(const float*)d_in[1],  (const float*)d_in[4],
                             (const float*)d_in[7],  (const float*)d_in[10],
                             (const float*)d_in[13]};
    const float* lat_b[5] = {(const float*)d_in[2],  (const float*)d_in[5],
                             (const float*)d_in[8],  (const float*)d_in[11],
                             (const float*)d_in[14]};
    const float* bif_dw  = (const float*)d_in[15];
    const float* bif_pw  = (const float*)d_in[16];
    const float* bif_pb  = (const float*)d_in[17];
    const float* bif_fw2 = (const float*)d_in[18];
    const float* bif_fw3 = (const float*)d_in[19];
    const float* reg_tw  = (const float*)d_in[20];
    const float* reg_tb  = (const float*)d_in[21];
    const float* reg_ow  = (const float*)d_in[22];
    const float* reg_ob  = (const float*)d_in[23];
    const float* cls_tw  = (const float*)d_in[24];
    const float* cls_tb  = (const float*)d_in[25];
    const float* cls_ow  = (const float*)d_in[26];
    const float* cls_ob  = (const float*)d_in[27];

    const int CINL[5] = {40, 80, 112, 192, 320};
    const int KSL[5]  = {2, 3, 4, 6, 10};
    const int LATO[5] = {0, 6144, 15360, 27648, 46080};
    const int ROFF[5] = {0, 16384, 20480, 21504, 21760};
    const int ML[5]   = {16384, 4096, 1024, 256, 64};
    const size_t CONC = (size_t)CONC_ROWS * 96;

    ushort* ws = (ushort*)d_ws;
    size_t off = 0;
    ushort* CA = ws + off; off += CONC;
    ushort* CB = ws + off; off += CONC;
    ushort* T4 = ws + off; off += (size_t)4096 * 96;
    ushort* T5 = ws + off; off += (size_t)1024 * 96;
    ushort* T6 = ws + off; off += (size_t)256 * 96;
    ushort* HXR0 = ws + off; off += CONC;
    ushort* HXR1 = ws + off; off += CONC;
    ushort* HXC0 = ws + off; off += CONC;
    ushort* HXC1 = ws + off; off += CONC;
    ushort* BP_PW  = ws + off; off += (size_t)24 * 9216;
    ushort* BP_TW  = ws + off; off += (size_t)8 * 82944;
    ushort* BP_RO  = ws + off; off += (size_t)82944;
    ushort* BP_CO  = ws + off; off += (size_t)746496;
    ushort* BP_LAT = ws + off; off += (size_t)76800;
    ushort* ZB     = ws + off; off += 96;
    (void)ws_size; (void)n_in; (void)in_sizes; (void)out_size;

    // ---- packing ----
    pack_pw_all_k<<<cdiv(24 * 9216, TPB), TPB, 0, stream>>>(bif_pw, BP_PW, 24 * 9216);
    pack_tw8_k<<<cdiv(8 * 82944, TPB), TPB, 0, stream>>>(reg_tw, cls_tw, BP_TW);
    pack3_k<<<cdiv(82944, TPB), TPB, 0, stream>>>(reg_ow, BP_RO, 96, 36, 82944);
    pack3_k<<<cdiv(746496, TPB), TPB, 0, stream>>>(cls_ow, BP_CO, 864, 810, 746496);
    pack_lat_k<<<cdiv(76800, TPB), TPB, 0, stream>>>(
        lat_w[0], lat_w[1], lat_w[2], lat_w[3], lat_w[4], BP_LAT);

    // ---- anchors + zero buffer ----
    float* cls_base = (float*)d_out;
    float* reg_base = cls_base + (size_t)4 * 49104 * 90;
    float* anc_base = reg_base + (size_t)4 * 49104 * 4;
    anchors_k<<<cdiv(49104, TPB), TPB, 0, stream>>>(anc_base, ZB);

    // ---- laterals ----
    for (int l = 0; l < 5; ++l) {
        int logHH = 2 * (6 - l);
        lateral_mfma_k<<<ML[l] / 64, 256, 0, stream>>>(
            c_in[l], BP_LAT + LATO[l], lat_b[l], CA + (size_t)ROFF[l] * 96,
            CINL[l], KSL[l], logHH);
    }

    // ---- BiFPN: 8 fused sep-conv steps per stage ----
    ushort* cur = CA; ushort* nxt = CB;
    for (int s = 0; s < 3; ++s) {
        const float* dws = bif_dw + (size_t)s * 8 * 792;
        const float* pbs = bif_pb + (size_t)s * 8 * 88;
        const float* f2  = bif_fw2 + (size_t)s * 10;
        const float* f3  = bif_fw3 + (size_t)s * 9;
        auto LP = [&](ushort* buf, int l) { return buf + (size_t)ROFF[l] * 96; };
        auto BPW = [&](int ci) { return BP_PW + (size_t)(s * 8 + ci) * 9216; };

        sepconv_k<0><<<ML[3] / 64, 256, 0, stream>>>(
            LP(cur, 3), LP(cur, 4), nullptr, f2 + 0, dws + 0 * 792, BPW(0), pbs + 0 * 88, T6, 3);
        sepconv_k<0><<<ML[2] / 64, 256, 0, stream>>>(
            LP(cur, 2), T6, nullptr, f2 + 2, dws + 1 * 792, BPW(1), pbs + 1 * 88, T5, 4);
        sepconv_k<0><<<ML[1] / 64, 256, 0, stream>>>(
            LP(cur, 1), T5, nullptr, f2 + 4, dws + 2 * 792, BPW(2), pbs + 2 * 88, T4, 5);
        sepconv_k<0><<<ML[0] / 64, 256, 0, stream>>>(
            LP(cur, 0), T4, nullptr, f2 + 6, dws + 3 * 792, BPW(3), pbs + 3 * 88, LP(nxt, 0), 6);
        sepconv_k<2><<<ML[1] / 64, 256, 0, stream>>>(
            LP(cur, 1), T4, LP(nxt, 0), f3 + 0, dws + 4 * 792, BPW(4), pbs + 4 * 88, LP(nxt, 1), 5);
        sepconv_k<2><<<ML[2] / 64, 256, 0, stream>>>(
            LP(cur, 2), T5, LP(nxt, 1), f3 + 3, dws + 5 * 792, BPW(5), pbs + 5 * 88, LP(nxt, 2), 4);
        sepconv_k<2><<<ML[3] / 64, 256, 0, stream>>>(
            LP(cur, 3), T6, LP(nxt, 2), f3 + 6, dws + 6 * 792, BPW(6), pbs + 6 * 88, LP(nxt, 3), 3);
        sepconv_k<1><<<ML[4] / 64, 256, 0, stream>>>(
            LP(cur, 4), LP(nxt, 3), nullptr, f2 + 8, dws + 7 * 792, BPW(7), pbs + 7 * 88, LP(nxt, 4), 2);

        ushort* tp = cur; cur = nxt; nxt = tp;
    }

    // ---- heads: direct-load towers, then fused reg+cls output convs ----
    const int GB = CONC_ROWS / 64;  // 341
    ushort* hxr[2] = {HXR0, HXR1};
    ushort* hxc[2] = {HXC0, HXC1};
    const ushort* xr = cur;
    const ushort* xc = cur;
    for (int i = 0; i < 4; ++i) {
        tower_direct_k<<<dim3(GB, 2), 256, 0, stream>>>(
            xr, xc, BP_TW + (size_t)i * 82944, BP_TW + (size_t)(4 + i) * 82944,
            reg_tb + i * 88, cls_tb + i * 88, hxr[i & 1], hxc[i & 1], ZB);
        xr = hxr[i & 1]; xc = hxc[i & 1];
    }
    heads_out_k<<<dim3(GB, 10), 256, 0, stream>>>(
        xr, xc, BP_RO, BP_CO, reg_ob, cls_ob, reg_base, cls_base, ZB);
}

// Round 7
// 647.884 us; speedup vs baseline: 1.1187x; 1.1187x over previous
//
#include <hip/hip_runtime.h>
#include <math.h>

#define TPB 256
static inline int cdiv(int a, int b) { return (a + b - 1) / b; }

typedef __attribute__((ext_vector_type(8))) short short8;
typedef __attribute__((ext_vector_type(4))) float floatx4;

__device__ __forceinline__ float bf2f(ushort u) {
    union { unsigned int u; float f; } v; v.u = ((unsigned int)u) << 16; return v.f;
}
__device__ __forceinline__ ushort f2bf(float f) {
    union { float f; unsigned int u; } v; v.f = f;
    unsigned int r = (v.u + 0x7FFFu + ((v.u >> 16) & 1u)) >> 16;
    return (ushort)r;
}

// Concatenated pyramid layout: rows [0,16384) l0(H=64), [16384,20480) l1(H=32),
// [20480,21504) l2(H=16), [21504,21760) l3(H=8), [21760,21824) l4(H=4).
#define CONC_ROWS 21824
__device__ __forceinline__ void lvl_of(int row, int& lvl, int& base) {
    lvl = 0; base = 0;
    if (row >= 16384) { lvl = 1; base = 16384; }
    if (row >= 20480) { lvl = 2; base = 20480; }
    if (row >= 21504) { lvl = 3; base = 21504; }
    if (row >= 21760) { lvl = 4; base = 21760; }
}
__constant__ int LOFFc[5] = {0, 36864, 46080, 48384, 48960};

// B slab per tap: [3ks][4g][96n][8j] = 9216 ushorts = 18432 B = 1152 x 16B
#define BSLAB 9216

// async global->LDS 16B DMA (wave-uniform LDS base + lane*16 — our staging
// pattern is lane-contiguous so this holds)
__device__ __forceinline__ void gld_lds16(const ushort* g, ushort* l) {
    __builtin_amdgcn_global_load_lds(
        (const __attribute__((address_space(1))) unsigned int*)g,
        (__attribute__((address_space(3))) unsigned int*)l, 16, 0, 0);
}

// ---------------------------------------------------------------------------
// Weight packing. Slab order (tap outer): Bp[(((tap*3+ks)*4+g)*Ntot + n)*8 + j]
// ---------------------------------------------------------------------------
__global__ void pack3_k(const float* __restrict__ w, ushort* __restrict__ Bp,
                        int Ntot, int CO, int total) {
    int idx = blockIdx.x * blockDim.x + threadIdx.x;
    if (idx >= total) return;
    int j = idx & 7; int t = idx >> 3;
    int n = t % Ntot; t /= Ntot;
    int g = t & 3; t >>= 2;
    int ks = t % 3; int tap = t / 3;
    int ci = ks * 32 + g * 8 + j;
    float v = (ci < 88 && n < CO) ? w[((size_t)n * 88 + ci) * 9 + tap] : 0.f;
    Bp[idx] = f2bf(v);
}

// cls out conv: [9 nb][9 tap][3 ks][4 g][96 n][8 j]; co = nb*96+n
__global__ void pack_cls_k(const float* __restrict__ w, ushort* __restrict__ Bp) {
    int idx = blockIdx.x * blockDim.x + threadIdx.x;
    if (idx >= 746496) return;
    int j = idx & 7; int t = idx >> 3;
    int n = t % 96; t /= 96;
    int g = t & 3; t >>= 2;
    int ks = t % 3; t /= 3;
    int tap = t % 9; int nb = t / 9;
    int ci = ks * 32 + g * 8 + j;
    int co = nb * 96 + n;
    float v = (ci < 88 && co < 810) ? w[((size_t)co * 88 + ci) * 9 + tap] : 0.f;
    Bp[idx] = f2bf(v);
}

__global__ void pack_tw8_k(const float* __restrict__ rw, const float* __restrict__ cw,
                           ushort* __restrict__ Bp) {
    int idx = blockIdx.x * blockDim.x + threadIdx.x;
    if (idx >= 8 * 82944) return;
    int i = idx / 82944; int r = idx - i * 82944;
    const float* w = (i < 4) ? rw + (size_t)i * 69696 : cw + (size_t)(i - 4) * 69696;
    int j = r & 7; int t = r >> 3;
    int n = t % 96; t /= 96;
    int g = t & 3; t >>= 2;
    int ks = t % 3; int tap = t / 3;
    int ci = ks * 32 + g * 8 + j;
    float v = (ci < 88 && n < 88) ? w[((size_t)n * 88 + ci) * 9 + tap] : 0.f;
    Bp[idx] = f2bf(v);
}

// 24 BiFPN pointwise convs -> 24 x [3ks][4g][96n][8j]
__global__ void pack_pw_all_k(const float* __restrict__ pw, ushort* __restrict__ Bp,
                              int total) {
    int idx = blockIdx.x * blockDim.x + threadIdx.x;
    if (idx >= total) return;
    int cid = idx / BSLAB; int r = idx - cid * BSLAB;
    int j = r & 7; int t = r >> 3;
    int n = t % 96; t /= 96;
    int g = t & 3; int ks = t >> 2;
    int ci = ks * 32 + g * 8 + j;
    float v = (ci < 88 && n < 88) ? pw[(size_t)cid * 7744 + n * 88 + ci] : 0.f;
    Bp[idx] = f2bf(v);
}

// 5 lateral 1x1 convs, K padded to 32: per level [KS][4g][96n][8j]
__global__ void pack_lat_k(const float* __restrict__ w3, const float* __restrict__ w4,
                           const float* __restrict__ w5, const float* __restrict__ w6,
                           const float* __restrict__ w7, ushort* __restrict__ Bp) {
    int idx = blockIdx.x * blockDim.x + threadIdx.x;
    if (idx >= 76800) return;
    int l, off;
    if (idx < 6144)       { l = 0; off = 0; }
    else if (idx < 15360) { l = 1; off = 6144; }
    else if (idx < 27648) { l = 2; off = 15360; }
    else if (idx < 46080) { l = 3; off = 27648; }
    else                  { l = 4; off = 46080; }
    const float* w = l == 0 ? w3 : l == 1 ? w4 : l == 2 ? w5 : l == 3 ? w6 : w7;
    const int cins[5] = {40, 80, 112, 192, 320};
    int Cin = cins[l];
    int r = idx - off;
    int j = r & 7; int t = r >> 3;
    int n = t % 96; t /= 96;
    int g = t & 3; int ks = t >> 2;
    int ci = ks * 32 + g * 8 + j;
    float v = (ci < Cin && n < 88) ? w[(size_t)n * Cin + ci] : 0.f;
    Bp[idx] = f2bf(v);
}

// ---------------------------------------------------------------------------
// Lateral conv as MFMA implicit GEMM: NCHW fp32 -> NHWC96 bf16, no act.
// ---------------------------------------------------------------------------
__global__ __launch_bounds__(256)
void lateral_mfma_k(const float* __restrict__ x, const ushort* __restrict__ Bp,
                    const float* __restrict__ bias, ushort* __restrict__ out,
                    int Cin, int KS, int logHH) {
    __shared__ ushort As[64 * 40];
    int tid = threadIdx.x;
    int m0 = blockIdx.x * 64;
    int lane = tid & 63, l15 = lane & 15, g = (lane >> 4) & 3;
    int wave = tid >> 6, wm = wave & 1, wn = wave >> 1;
    floatx4 acc[2][3];
#pragma unroll
    for (int a = 0; a < 2; ++a)
#pragma unroll
        for (int b = 0; b < 3; ++b) acc[a][b] = (floatx4){0.f, 0.f, 0.f, 0.f};
    const short8* Bq = (const short8*)Bp;

    int p = m0 + lane;
    int n = p >> logHH, pp = p & ((1 << logHH) - 1);
    const float* xp = x + (((size_t)n * Cin) << logHH) + pp;

    for (int ks = 0; ks < KS; ++ks) {
        __syncthreads();
#pragma unroll
        for (int it = 0; it < 8; ++it) {
            int ciL = (tid >> 6) + it * 4;
            int ci = ks * 32 + ciL;
            float v = (ci < Cin) ? xp[(size_t)ci << logHH] : 0.f;
            As[lane * 40 + ciL] = f2bf(v);
        }
        __syncthreads();
        short8 a0 = *(const short8*)(&As[(wm * 32 + l15) * 40 + g * 8]);
        short8 a1 = *(const short8*)(&As[(wm * 32 + 16 + l15) * 40 + g * 8]);
        int bbase = (ks * 4 + g) * 96 + wn * 48 + l15;
#pragma unroll
        for (int nf = 0; nf < 3; ++nf) {
            short8 b = Bq[bbase + nf * 16];
            acc[0][nf] = __builtin_amdgcn_mfma_f32_16x16x32_bf16(a0, b, acc[0][nf], 0, 0, 0);
            acc[1][nf] = __builtin_amdgcn_mfma_f32_16x16x32_bf16(a1, b, acc[1][nf], 0, 0, 0);
        }
    }
    float bc[3];
#pragma unroll
    for (int nf = 0; nf < 3; ++nf) {
        int c = wn * 48 + nf * 16 + l15;
        bc[nf] = (c < 88) ? bias[c] : 0.f;
    }
#pragma unroll
    for (int mf = 0; mf < 2; ++mf)
#pragma unroll
        for (int r = 0; r < 4; ++r) {
            int pl = m0 + wm * 32 + mf * 16 + g * 4 + r;
#pragma unroll
            for (int nf = 0; nf < 3; ++nf) {
                int c = wn * 48 + nf * 16 + l15;
                out[(size_t)pl * 96 + c] = f2bf(acc[mf][nf][r] + bc[nf]);
            }
        }
}

// ---------------------------------------------------------------------------
// Fully fused BiFPN step: fuse-op -> depthwise 3x3 -> pointwise MFMA + ReLU.
// MODE 0: 2-in (a + up2(b)); 1: 2-in (a + down2(b)); 2: 3-in (a + b + down2(c)).
// ---------------------------------------------------------------------------
template <int MODE>
__global__ __launch_bounds__(256, 2)
void sepconv_k(const ushort* __restrict__ a, const ushort* __restrict__ bsrc,
               const ushort* __restrict__ csrc, const float* __restrict__ fw,
               const float* __restrict__ dww, const ushort* __restrict__ Bp,
               const float* __restrict__ pbias, ushort* __restrict__ out,
               int logW) {
    __shared__ ushort Fs[195 * 104];   // fused input + halo; row 194 = zeros
    __shared__ ushort Ds[64 * 104];    // depthwise output (pw A-tile)
    __shared__ ushort Dwb[108 * 8];    // dw weights bf16 [cg][tap][8]
    int tid = threadIdx.x;
    int W = 1 << logW, HH = W * W, log2HH = 2 * logW;
    int Mlv = 4 * HH;
    int HB = W + 1;
    int RS = 64 + 2 * HB;
    int pl0 = blockIdx.x * 64;
    float w0 = fmaxf(fw[0], 0.f), w1 = fmaxf(fw[1], 0.f);
    float w2 = (MODE == 2) ? fmaxf(fw[2], 0.f) : 0.f;
    float inv = 1.f / (w0 + w1 + w2 + 1e-4f);
    float w0i = w0 * inv, w1i = w1 * inv, w2i = w2 * inv;

    if (tid < 13) *(uint4*)(&Fs[194 * 104 + tid * 8]) = (uint4){0u, 0u, 0u, 0u};
    for (int i = tid; i < 108; i += 256) {
        int cg = i / 9, tap = i - cg * 9;
        ushort tmp[8];
#pragma unroll
        for (int j = 0; j < 8; ++j) {
            int c = cg * 8 + j;
            tmp[j] = (c < 88) ? f2bf(dww[c * 9 + tap]) : (ushort)0;
        }
        *(uint4*)(&Dwb[i * 8]) = *(uint4*)tmp;
    }
    for (int i = tid; i < RS * 12; i += 256) {
        int row = i / 12, cg = i - row * 12;
        int pl = pl0 - HB + row;
        uint4 res = {0u, 0u, 0u, 0u};
        if (pl >= 0 && pl < Mlv) {
            int n = pl >> log2HH, pp = pl & (HH - 1);
            int y = pp >> logW, x = pp & (W - 1);
            uint4 av = *(const uint4*)(a + (size_t)pl * 96 + cg * 8);
            const ushort* au = (const ushort*)&av;
            float f[8];
            if (MODE == 0) {
                int Wh = W >> 1;
                int bp = (n << (log2HH - 2)) + (y >> 1) * Wh + (x >> 1);
                uint4 bv = *(const uint4*)(bsrc + (size_t)bp * 96 + cg * 8);
                const ushort* bu = (const ushort*)&bv;
#pragma unroll
                for (int j = 0; j < 8; ++j)
                    f[j] = w0i * bf2f(au[j]) + w1i * bf2f(bu[j]);
            } else {
                int W2 = W << 1;
                const ushort* q = (MODE == 1 ? bsrc : csrc) +
                    ((size_t)((n << (log2HH + 2)) + (2 * y) * W2 + 2 * x)) * 96 + cg * 8;
                uint4 q0 = *(const uint4*)(q);
                uint4 q1 = *(const uint4*)(q + 96);
                uint4 q2 = *(const uint4*)(q + (size_t)W2 * 96);
                uint4 q3 = *(const uint4*)(q + (size_t)W2 * 96 + 96);
                const ushort* u0 = (const ushort*)&q0; const ushort* u1 = (const ushort*)&q1;
                const ushort* u2 = (const ushort*)&q2; const ushort* u3 = (const ushort*)&q3;
                if (MODE == 1) {
#pragma unroll
                    for (int j = 0; j < 8; ++j) {
                        float m = fmaxf(fmaxf(bf2f(u0[j]), bf2f(u1[j])),
                                        fmaxf(bf2f(u2[j]), bf2f(u3[j])));
                        f[j] = w0i * bf2f(au[j]) + w1i * m;
                    }
                } else {
                    uint4 b2v = *(const uint4*)(bsrc + (size_t)pl * 96 + cg * 8);
                    const ushort* b2u = (const ushort*)&b2v;
#pragma unroll
                    for (int j = 0; j < 8; ++j) {
                        float m = fmaxf(fmaxf(bf2f(u0[j]), bf2f(u1[j])),
                                        fmaxf(bf2f(u2[j]), bf2f(u3[j])));
                        f[j] = w0i * bf2f(au[j]) + w1i * bf2f(b2u[j]) + w2i * m;
                    }
                }
            }
            ushort tmp[8];
#pragma unroll
            for (int j = 0; j < 8; ++j) tmp[j] = f2bf(f[j]);
            res = *(uint4*)tmp;
        }
        *(uint4*)(&Fs[row * 104 + cg * 8]) = res;
    }
    __syncthreads();
    // depthwise 3x3 -> Ds
    for (int i = tid; i < 768; i += 256) {
        int row = i / 12, cg = i - row * 12;
        int pl = pl0 + row;
        int pp = pl & (HH - 1);
        int y = pp >> logW, x = pp & (W - 1);
        float acc8[8] = {0.f, 0.f, 0.f, 0.f, 0.f, 0.f, 0.f, 0.f};
        if (cg < 11) {
#pragma unroll
            for (int tap = 0; tap < 9; ++tap) {
                int dy = tap / 3 - 1, dx = tap % 3 - 1;
                int sy = y + dy, sx = x + dx;
                bool pred = ((unsigned)sy < (unsigned)W) && ((unsigned)sx < (unsigned)W);
                int rsel = pred ? (row + HB + dy * W + dx) : 194;
                short8 fv = *(const short8*)(&Fs[rsel * 104 + cg * 8]);
                short8 wv = *(const short8*)(&Dwb[(cg * 9 + tap) * 8]);
#pragma unroll
                for (int j = 0; j < 8; ++j)
                    acc8[j] = fmaf(bf2f((ushort)fv[j]), bf2f((ushort)wv[j]), acc8[j]);
            }
        }
        ushort tmp[8];
#pragma unroll
        for (int j = 0; j < 8; ++j) tmp[j] = f2bf(acc8[j]);
        *(uint4*)(&Ds[row * 104 + cg * 8]) = *(uint4*)tmp;
    }
    __syncthreads();
    // pointwise MFMA (Mt=64, N=96, K=96) + bias + ReLU
    int lane = tid & 63, l15 = lane & 15, g = (lane >> 4) & 3;
    int wave = tid >> 6, wm = wave & 1, wn = wave >> 1;
    floatx4 acc[2][3];
#pragma unroll
    for (int aa = 0; aa < 2; ++aa)
#pragma unroll
        for (int bb = 0; bb < 3; ++bb) acc[aa][bb] = (floatx4){0.f, 0.f, 0.f, 0.f};
    const short8* Bq = (const short8*)Bp;
#pragma unroll
    for (int ks = 0; ks < 3; ++ks) {
        int k = ks * 32 + g * 8;
        short8 a0 = *(const short8*)(&Ds[(wm * 32 + l15) * 104 + k]);
        short8 a1 = *(const short8*)(&Ds[(wm * 32 + 16 + l15) * 104 + k]);
        int bbase = (ks * 4 + g) * 96 + wn * 48 + l15;
#pragma unroll
        for (int nf = 0; nf < 3; ++nf) {
            short8 b = Bq[bbase + nf * 16];
            acc[0][nf] = __builtin_amdgcn_mfma_f32_16x16x32_bf16(a0, b, acc[0][nf], 0, 0, 0);
            acc[1][nf] = __builtin_amdgcn_mfma_f32_16x16x32_bf16(a1, b, acc[1][nf], 0, 0, 0);
        }
    }
    float bc[3];
#pragma unroll
    for (int nf = 0; nf < 3; ++nf) {
        int c = wn * 48 + nf * 16 + l15;
        bc[nf] = (c < 88) ? pbias[c] : 0.f;
    }
#pragma unroll
    for (int mf = 0; mf < 2; ++mf)
#pragma unroll
        for (int r = 0; r < 4; ++r) {
            int pl = pl0 + wm * 32 + mf * 16 + g * 4 + r;
#pragma unroll
            for (int nf = 0; nf < 3; ++nf) {
                int c = wn * 48 + nf * 16 + l15;
                out[(size_t)pl * 96 + c] = f2bf(fmaxf(acc[mf][nf][r] + bc[nf], 0.f));
            }
        }
}

// ---------------------------------------------------------------------------
// Pipelined tower conv 3x3: B slabs DMA'd to LDS one tap ahead
// (global_load_lds, double buffer), A direct from global (L1-resident across
// taps). One barrier per tap. Dual-head via blockIdx.y.
// ---------------------------------------------------------------------------
__global__ __launch_bounds__(256)
void tower_pipe_k(const ushort* __restrict__ inR, const ushort* __restrict__ inC,
                  const ushort* __restrict__ BpR, const ushort* __restrict__ BpC,
                  const float* __restrict__ bR, const float* __restrict__ bC,
                  ushort* __restrict__ outR, ushort* __restrict__ outC,
                  const ushort* __restrict__ zb) {
    __shared__ __align__(16) ushort Bs[2][BSLAB];
    int head = blockIdx.y;
    const ushort* in = head ? inC : inR;
    const ushort* Bg = head ? BpC : BpR;
    const float* bias = head ? bC : bR;
    ushort* out = head ? outC : outR;
    int tid = threadIdx.x;
    int m0 = blockIdx.x * 64;
    int lvl, base; lvl_of(m0, lvl, base);
    int logW = 6 - lvl, W = 1 << logW, HH = W * W;
    int pl0 = m0 - base;
    int lane = tid & 63, l15 = lane & 15, g = (lane >> 4) & 3;
    int wave = tid >> 6, wm = wave & 1, wn = wave >> 1;
    int ym[2], xm[2];
    const ushort* pbase[2];
#pragma unroll
    for (int mf = 0; mf < 2; ++mf) {
        int pl = pl0 + wm * 32 + mf * 16 + l15;
        int pp = pl & (HH - 1);
        ym[mf] = pp >> logW; xm[mf] = pp & (W - 1);
        pbase[mf] = in + (size_t)(base + pl) * 96 + g * 8;
    }
    const ushort* zbg = zb + g * 8;
    int fragoff = (g * 96 + wn * 48 + l15) * 8;   // + ks*4*96*8 per ks

    // stage tap slab into LDS buffer
    auto stage = [&](int tap) {
        const ushort* src = Bg + tap * BSLAB;
        ushort* dst = (ushort*)Bs[tap & 1];
#pragma unroll
        for (int it = 0; it < 5; ++it) {
            int c = tid + it * 256;
            if (c < 1152) gld_lds16(src + (size_t)c * 8, dst + (size_t)c * 8);
        }
    };

    floatx4 acc[2][3];
#pragma unroll
    for (int aa = 0; aa < 2; ++aa)
#pragma unroll
        for (int bb = 0; bb < 3; ++bb) acc[aa][bb] = (floatx4){0.f, 0.f, 0.f, 0.f};

    stage(0);
    __syncthreads();
#pragma unroll
    for (int tap = 0; tap < 9; ++tap) {
        if (tap < 8) stage(tap + 1);
        const ushort* Bb = (const ushort*)Bs[tap & 1];
        const int dy = tap / 3 - 1, dx = tap % 3 - 1;
        int off96 = (dy * W + dx) * 96;
        const ushort* ap[2];
#pragma unroll
        for (int mf = 0; mf < 2; ++mf) {
            bool pred = ((unsigned)(ym[mf] + dy) < (unsigned)W) &&
                        ((unsigned)(xm[mf] + dx) < (unsigned)W);
            ap[mf] = pred ? (pbase[mf] + off96) : zbg;
        }
#pragma unroll
        for (int ks = 0; ks < 3; ++ks) {
            short8 a0 = *(const short8*)(ap[0] + ks * 32);
            short8 a1 = *(const short8*)(ap[1] + ks * 32);
            const ushort* bb = Bb + ks * 3072 + fragoff;
#pragma unroll
            for (int nf = 0; nf < 3; ++nf) {
                short8 b = *(const short8*)(bb + nf * 128);
                acc[0][nf] = __builtin_amdgcn_mfma_f32_16x16x32_bf16(a0, b, acc[0][nf], 0, 0, 0);
                acc[1][nf] = __builtin_amdgcn_mfma_f32_16x16x32_bf16(a1, b, acc[1][nf], 0, 0, 0);
            }
        }
        __syncthreads();   // drains tap+1 staging; protects buffer reuse
    }
    float bc[3];
#pragma unroll
    for (int nf = 0; nf < 3; ++nf) {
        int c = wn * 48 + nf * 16 + l15;
        bc[nf] = (c < 88) ? bias[c] : 0.f;
    }
#pragma unroll
    for (int mf = 0; mf < 2; ++mf)
#pragma unroll
        for (int r = 0; r < 4; ++r) {
            int pl = pl0 + wm * 32 + mf * 16 + g * 4 + r;
#pragma unroll
            for (int nf = 0; nf < 3; ++nf) {
                int c = wn * 48 + nf * 16 + l15;
                out[(size_t)(base + pl) * 96 + c] = f2bf(fmaxf(acc[mf][nf][r] + bc[nf], 0.f));
            }
        }
}

// ---------------------------------------------------------------------------
// Pipelined fused output heads: grid (341, 10). y=0 -> regression, y>=1 ->
// cls n-block y-1 (+sigmoid). Same B-LDS pipeline; scatter to (B,49104,OC).
// ---------------------------------------------------------------------------
__global__ __launch_bounds__(256)
void heads_pipe_k(const ushort* __restrict__ xr, const ushort* __restrict__ xc,
                  const ushort* __restrict__ BpR, const ushort* __restrict__ BpC,
                  const float* __restrict__ bR, const float* __restrict__ bC,
                  float* __restrict__ outR, float* __restrict__ outC,
                  const ushort* __restrict__ zb) {
    __shared__ __align__(16) ushort Bs[2][BSLAB];
    int yb = blockIdx.y;
    bool isReg = (yb == 0);
    const ushort* in = isReg ? xr : xc;
    const ushort* Bg = isReg ? BpR : (BpC + (size_t)(yb - 1) * 9 * BSLAB);
    const float* bias = isReg ? bR : bC;
    float* outb = isReg ? outR : outC;
    const int C9 = isReg ? 36 : 810;
    const int OC = isReg ? 4 : 90;
    const int n0b = isReg ? 0 : (yb - 1) * 96;

    int tid = threadIdx.x;
    int m0 = blockIdx.x * 64;
    int lvl, base; lvl_of(m0, lvl, base);
    int logW = 6 - lvl, W = 1 << logW, HH = W * W, log2HH = 2 * logW;
    int pl0 = m0 - base;
    int lane = tid & 63, l15 = lane & 15, g = (lane >> 4) & 3;
    int wave = tid >> 6, wm = wave & 1, wn = wave >> 1;
    int ym[2], xm[2];
    const ushort* pbase[2];
#pragma unroll
    for (int mf = 0; mf < 2; ++mf) {
        int pl = pl0 + wm * 32 + mf * 16 + l15;
        int pp = pl & (HH - 1);
        ym[mf] = pp >> logW; xm[mf] = pp & (W - 1);
        pbase[mf] = in + (size_t)(base + pl) * 96 + g * 8;
    }
    const ushort* zbg = zb + g * 8;
    int fragoff = (g * 96 + wn * 48 + l15) * 8;

    auto stage = [&](int tap) {
        const ushort* src = Bg + tap * BSLAB;
        ushort* dst = (ushort*)Bs[tap & 1];
#pragma unroll
        for (int it = 0; it < 5; ++it) {
            int c = tid + it * 256;
            if (c < 1152) gld_lds16(src + (size_t)c * 8, dst + (size_t)c * 8);
        }
    };

    floatx4 acc[2][3];
#pragma unroll
    for (int aa = 0; aa < 2; ++aa)
#pragma unroll
        for (int bb = 0; bb < 3; ++bb) acc[aa][bb] = (floatx4){0.f, 0.f, 0.f, 0.f};

    stage(0);
    __syncthreads();
#pragma unroll
    for (int tap = 0; tap < 9; ++tap) {
        if (tap < 8) stage(tap + 1);
        const ushort* Bb = (const ushort*)Bs[tap & 1];
        const int dy = tap / 3 - 1, dx = tap % 3 - 1;
        int off96 = (dy * W + dx) * 96;
        const ushort* ap[2];
#pragma unroll
        for (int mf = 0; mf < 2; ++mf) {
            bool pred = ((unsigned)(ym[mf] + dy) < (unsigned)W) &&
                        ((unsigned)(xm[mf] + dx) < (unsigned)W);
            ap[mf] = pred ? (pbase[mf] + off96) : zbg;
        }
#pragma unroll
        for (int ks = 0; ks < 3; ++ks) {
            short8 a0 = *(const short8*)(ap[0] + ks * 32);
            short8 a1 = *(const short8*)(ap[1] + ks * 32);
            const ushort* bb = Bb + ks * 3072 + fragoff;
#pragma unroll
            for (int nf = 0; nf < 3; ++nf) {
                short8 b = *(const short8*)(bb + nf * 128);
                acc[0][nf] = __builtin_amdgcn_mfma_f32_16x16x32_bf16(a0, b, acc[0][nf], 0, 0, 0);
                acc[1][nf] = __builtin_amdgcn_mfma_f32_16x16x32_bf16(a1, b, acc[1][nf], 0, 0, 0);
            }
        }
        __syncthreads();
    }
#pragma unroll
    for (int nf = 0; nf < 3; ++nf) {
        int c = n0b + wn * 48 + nf * 16 + l15;
        if (c >= C9) continue;
        float bcv = bias[c];
        int a = c / OC, kk = c - a * OC;
#pragma unroll
        for (int mf = 0; mf < 2; ++mf)
#pragma unroll
            for (int r = 0; r < 4; ++r) {
                int pl = pl0 + wm * 32 + mf * 16 + g * 4 + r;
                int n = pl >> log2HH, pp = pl & (HH - 1);
                float v = acc[mf][nf][r] + bcv;
                if (!isReg) v = 1.f / (1.f + expf(-v));
                outb[((size_t)n * 49104 + LOFFc[lvl] + (size_t)pp * 9 + a) * OC + kk] = v;
            }
    }
}

// ---------------------------------------------------------------------------
// anchors + zero-buffer init (zb: 96 ushorts = 48 uints)
__global__ void anchors_k(float* __restrict__ out, ushort* __restrict__ zb) {
    int idx = blockIdx.x * blockDim.x + threadIdx.x;
    if (idx < 48) ((unsigned int*)zb)[idx] = 0u;
    if (idx >= 49104) return;
    const int offs[6] = {0, 36864, 46080, 48384, 48960, 49104};
    int l = 0;
    while (idx >= offs[l + 1]) ++l;
    int j = idx - offs[l];
    int a = j % 9;
    int p = j / 9;
    int fs = 64 >> l;
    int stride = 8 << l;
    float size = (float)(32 << l);
    int ix = p % fs, iy = p / fs;
    float cx = (ix + 0.5f) * (float)stride;
    float cy = (iy + 0.5f) * (float)stride;
    const float scl[3] = {1.0f, 1.2599210498948732f, 1.5874010519681994f};
    const float sqr[3] = {0.7071067811865476f, 1.0f, 1.4142135623730951f};
    int r = a / 3, s = a % 3;
    float w = size * scl[s] / sqr[r];
    float h = size * scl[s] * sqr[r];
    float* o = out + (size_t)idx * 4;
    o[0] = cx - 0.5f * w;
    o[1] = cy - 0.5f * h;
    o[2] = cx + 0.5f * w;
    o[3] = cy + 0.5f * h;
}

// ---------------------------------------------------------------------------

extern "C" void kernel_launch(void* const* d_in, const int* in_sizes, int n_in,
                              void* d_out, int out_size, void* d_ws, size_t ws_size,
                              hipStream_t stream) {
    const float* c_in[5]  = {(const float*)d_in[0],  (const float*)d_in[3],
                             (const float*)d_in[6],  (const float*)d_in[9],
                             (const float*)d_in[12]};
    const float* lat_w[5] = {(const float*)d_in[1],  (const float*)d_in[4],
                             (const float*)d_in[7],  (const float*)d_in[10],
                             (const float*)d_in[13]};
    const float* lat_b[5] = {(const float*)d_in[2],  (const float*)d_in[5],
                             (const float*)d_in[8],  (const float*)d_in[11],
                             (const float*)d_in[14]};
    const float* bif_dw  = (const float*)d_in[15];
    const float* bif_pw  = (const float*)d_in[16];
    const float* bif_pb  = (const float*)d_in[17];
    const float* bif_fw2 = (const float*)d_in[18];
    const float* bif_fw3 = (const float*)d_in[19];
    const float* reg_tw  = (const float*)d_in[20];
    const float* reg_tb  = (const float*)d_in[21];
    const float* reg_ow  = (const float*)d_in[22];
    const float* reg_ob  = (const float*)d_in[23];
    const float* cls_tw  = (const float*)d_in[24];
    const float* cls_tb  = (const float*)d_in[25];
    const float* cls_ow  = (const float*)d_in[26];
    const float* cls_ob  = (const float*)d_in[27];

    const int CINL[5] = {40, 80, 112, 192, 320};
    const int KSL[5]  = {2, 3, 4, 6, 10};
    const int LATO[5] = {0, 6144, 15360, 27648, 46080};
    const int ROFF[5] = {0, 16384, 20480, 21504, 21760};
    const int ML[5]   = {16384, 4096, 1024, 256, 64};
    const size_t CONC = (size_t)CONC_ROWS * 96;

    ushort* ws = (ushort*)d_ws;
    size_t off = 0;
    ushort* CA = ws + off; off += CONC;
    ushort* CB = ws + off; off += CONC;
    ushort* T4 = ws + off; off += (size_t)4096 * 96;
    ushort* T5 = ws + off; off += (size_t)1024 * 96;
    ushort* T6 = ws + off; off += (size_t)256 * 96;
    ushort* HXR0 = ws + off; off += CONC;
    ushort* HXR1 = ws + off; off += CONC;
    ushort* HXC0 = ws + off; off += CONC;
    ushort* HXC1 = ws + off; off += CONC;
    ushort* BP_PW  = ws + off; off += (size_t)24 * BSLAB;
    ushort* BP_TW  = ws + off; off += (size_t)8 * 82944;
    ushort* BP_RO  = ws + off; off += (size_t)82944;
    ushort* BP_CO  = ws + off; off += (size_t)746496;
    ushort* BP_LAT = ws + off; off += (size_t)76800;
    ushort* ZB     = ws + off; off += 96;
    (void)ws_size; (void)n_in; (void)in_sizes; (void)out_size;

    // ---- packing ----
    pack_pw_all_k<<<cdiv(24 * BSLAB, TPB), TPB, 0, stream>>>(bif_pw, BP_PW, 24 * BSLAB);
    pack_tw8_k<<<cdiv(8 * 82944, TPB), TPB, 0, stream>>>(reg_tw, cls_tw, BP_TW);
    pack3_k<<<cdiv(82944, TPB), TPB, 0, stream>>>(reg_ow, BP_RO, 96, 36, 82944);
    pack_cls_k<<<cdiv(746496, TPB), TPB, 0, stream>>>(cls_ow, BP_CO);
    pack_lat_k<<<cdiv(76800, TPB), TPB, 0, stream>>>(
        lat_w[0], lat_w[1], lat_w[2], lat_w[3], lat_w[4], BP_LAT);

    // ---- anchors + zero buffer ----
    float* cls_base = (float*)d_out;
    float* reg_base = cls_base + (size_t)4 * 49104 * 90;
    float* anc_base = reg_base + (size_t)4 * 49104 * 4;
    anchors_k<<<cdiv(49104, TPB), TPB, 0, stream>>>(anc_base, ZB);

    // ---- laterals ----
    for (int l = 0; l < 5; ++l) {
        int logHH = 2 * (6 - l);
        lateral_mfma_k<<<ML[l] / 64, 256, 0, stream>>>(
            c_in[l], BP_LAT + LATO[l], lat_b[l], CA + (size_t)ROFF[l] * 96,
            CINL[l], KSL[l], logHH);
    }

    // ---- BiFPN: 8 fused sep-conv steps per stage ----
    ushort* cur = CA; ushort* nxt = CB;
    for (int s = 0; s < 3; ++s) {
        const float* dws = bif_dw + (size_t)s * 8 * 792;
        const float* pbs = bif_pb + (size_t)s * 8 * 88;
        const float* f2  = bif_fw2 + (size_t)s * 10;
        const float* f3  = bif_fw3 + (size_t)s * 9;
        auto LP = [&](ushort* buf, int l) { return buf + (size_t)ROFF[l] * 96; };
        auto BPW = [&](int ci) { return BP_PW + (size_t)(s * 8 + ci) * BSLAB; };

        sepconv_k<0><<<ML[3] / 64, 256, 0, stream>>>(
            LP(cur, 3), LP(cur, 4), nullptr, f2 + 0, dws + 0 * 792, BPW(0), pbs + 0 * 88, T6, 3);
        sepconv_k<0><<<ML[2] / 64, 256, 0, stream>>>(
            LP(cur, 2), T6, nullptr, f2 + 2, dws + 1 * 792, BPW(1), pbs + 1 * 88, T5, 4);
        sepconv_k<0><<<ML[1] / 64, 256, 0, stream>>>(
            LP(cur, 1), T5, nullptr, f2 + 4, dws + 2 * 792, BPW(2), pbs + 2 * 88, T4, 5);
        sepconv_k<0><<<ML[0] / 64, 256, 0, stream>>>(
            LP(cur, 0), T4, nullptr, f2 + 6, dws + 3 * 792, BPW(3), pbs + 3 * 88, LP(nxt, 0), 6);
        sepconv_k<2><<<ML[1] / 64, 256, 0, stream>>>(
            LP(cur, 1), T4, LP(nxt, 0), f3 + 0, dws + 4 * 792, BPW(4), pbs + 4 * 88, LP(nxt, 1), 5);
        sepconv_k<2><<<ML[2] / 64, 256, 0, stream>>>(
            LP(cur, 2), T5, LP(nxt, 1), f3 + 3, dws + 5 * 792, BPW(5), pbs + 5 * 88, LP(nxt, 2), 4);
        sepconv_k<2><<<ML[3] / 64, 256, 0, stream>>>(
            LP(cur, 3), T6, LP(nxt, 2), f3 + 6, dws + 6 * 792, BPW(6), pbs + 6 * 88, LP(nxt, 3), 3);
        sepconv_k<1><<<ML[4] / 64, 256, 0, stream>>>(
            LP(cur, 4), LP(nxt, 3), nullptr, f2 + 8, dws + 7 * 792, BPW(7), pbs + 7 * 88, LP(nxt, 4), 2);

        ushort* tp = cur; cur = nxt; nxt = tp;
    }

    // ---- heads: pipelined towers, then fused pipelined output convs ----
    const int GB = CONC_ROWS / 64;  // 341
    ushort* hxr[2] = {HXR0, HXR1};
    ushort* hxc[2] = {HXC0, HXC1};
    const ushort* xr = cur;
    const ushort* xc = cur;
    for (int i = 0; i < 4; ++i) {
        tower_pipe_k<<<dim3(GB, 2), 256, 0, stream>>>(
            xr, xc, BP_TW + (size_t)i * 82944, BP_TW + (size_t)(4 + i) * 82944,
            reg_tb + i * 88, cls_tb + i * 88, hxr[i & 1], hxc[i & 1], ZB);
        xr = hxr[i & 1]; xc = hxc[i & 1];
    }
    heads_pipe_k<<<dim3(GB, 10), 256, 0, stream>>>(
        xr, xc, BP_RO, BP_CO, reg_ob, cls_ob, reg_base, cls_base, ZB);
}